// Round 14
// baseline (285.213 us; speedup 1.0000x reference)
//
#include <hip/hip_runtime.h>

typedef float f32x4 __attribute__((ext_vector_type(4)));
typedef __bf16 bf16x8 __attribute__((ext_vector_type(8)));
typedef unsigned short ushort_t;

#define DEV_INLINE __device__ __forceinline__

constexpr int B_N  = 2;
constexpr int C3_N = 128;
constexpr int C2_N = 96;
constexpr int DZ_N = 32;
constexpr int H_N  = 24;
constexpr int W_N  = 24;
constexpr int K_N  = 8;
constexpr int E_N  = 256;
constexpr int HW_N = 576;

DEV_INLINE unsigned short f2bf(float x) {
  union { __bf16 b; unsigned short u; } v;
  v.b = (__bf16)x;
  return v.u;
}

// ---------------------------------------------------------------------------
// Fused: topo 3x3 conv (blocks 0..511) U weight packing (blocks 512..1407).
// Conv split 8 channel-chunks (2/CU) — R13, kept (small real gain).
// ---------------------------------------------------------------------------
__global__ __launch_bounds__(384) void pre_conv_pack(
    const float* __restrict__ F2, const float* __restrict__ W1,
    float* __restrict__ Hp,
    const float* __restrict__ Wq, const float* __restrict__ Wk,
    const float* __restrict__ Wv, const float* __restrict__ Wp,
    ushort_t* __restrict__ Wqp, ushort_t* __restrict__ Wkp,
    ushort_t* __restrict__ Wvp, ushort_t* __restrict__ Wpp) {
  __shared__ float simg[6][26][28];
  __shared__ float sw[16 * 97];
  const int bid0 = blockIdx.x;
  if (bid0 >= 512) {
    // ---- pack branch ----
    const int bblk = bid0 - 512, t = threadIdx.x;
    if (t < 256) {
      if (bblk < 256) {
        if (t < 128) Wqp[bblk * 128 + t] = f2bf(Wq[t * 256 + bblk]);
      } else if (bblk < 512) {
        const int n = bblk - 256;
        if (t < 96) Wkp[n * 96 + t] = f2bf(Wk[t * 256 + n]);
      } else if (bblk < 768) {
        const int n = bblk - 512;
        if (t < 96) Wvp[n * 96 + t] = f2bf(Wv[t * 256 + n]);
      } else {
        const int c = bblk - 768;
        Wpp[c * 256 + t] = f2bf(Wp[t * 128 + c]);
      }
    }
    return;
  }
  // ---- conv branch: cc(8) x tg(4) x bk(16) = 512 blocks ----
  const int bid = bid0;
  const int cc = bid & 7;            // 8 chunks of 12 channels
  const int tg = (bid >> 3) & 3;
  const int bk = bid >> 5;           // 0..15 = b*8 + k
  const int b = bk >> 3, k = bk & 7;
  const int tid = threadIdx.x;
  const int y = tid >> 4;            // 0..23
  const int tq = tid & 15;           // 0..15

  float acc[24];
#pragma unroll
  for (int i = 0; i < 24; i++) acc[i] = 0.f;

  float* simgf = &simg[0][0][0];
  for (int i = tid; i < 6 * 26 * 28; i += 384) simgf[i] = 0.f;
  __syncthreads();

  for (int ch = 0; ch < 2; ch++) {
    if (ch) __syncthreads();
    const int c0 = cc * 12 + ch * 6;
    for (int i = tid; i < 6 * 24 * 24; i += 384) {
      int c = i / 576, p = i - c * 576;
      int yy = p / 24, xx = p - yy * 24;
      simg[c][yy + 1][xx + 1] =
          F2[(((b * C2_N + c0 + c) * H_N + yy) * W_N + xx) * K_N + k];
    }
    for (int i = tid; i < 16 * 54; i += 384) {
      int t2 = i / 54, rest = i - t2 * 54;
      int c = rest / 9, q = rest - c * 9;
      sw[t2 * 97 + c * 12 + q] =
          W1[(tg * 16 + t2) * (C2_N * 9) + (c0 + c) * 9 + q];
    }
    __syncthreads();
#pragma unroll 1
    for (int c = 0; c < 6; c++) {
      float w[9];
#pragma unroll
      for (int q = 0; q < 9; q++) w[q] = sw[tq * 97 + c * 12 + q];
#pragma unroll
      for (int dy = 0; dy < 3; dy++) {
        float r[28];   // full padded row: cols 26,27 are zero pad (unused)
#pragma unroll
        for (int g = 0; g < 7; g++)
          *(float4*)&r[g * 4] = *(const float4*)&simg[c][y + dy][g * 4];
#pragma unroll
        for (int dx = 0; dx < 3; dx++) {
          float wv = w[dy * 3 + dx];
#pragma unroll
          for (int xx = 0; xx < 24; xx++)
            acc[xx] = fmaf(wv, r[xx + dx], acc[xx]);
        }
      }
    }
  }
  const int t = tg * 16 + tq;
  float* dst = &Hp[((cc * 16 + bk) * 64 + t) * HW_N + y * 24];
#pragma unroll
  for (int xx = 0; xx < 24; xx++) dst[xx] = acc[xx];
}

// ---------------------------------------------------------------------------
// Fused projections + topo tail:
//   blocks 0..143   = K+V projection path
//   blocks 144..159 = topo tail (8 partials)
//   blocks 160..735 = Q projection path
// R14: staging loops split load-all-THEN-convert — all 24/32 strided global
// loads issue back-to-back (full MLP, no vmcnt waits between them) instead
// of load-pair/convert/store interleave that kept only ~2-4 in flight.
// ---------------------------------------------------------------------------
__global__ __launch_bounds__(256) void proj_all(
    const float* __restrict__ F3, const float* __restrict__ F2,
    const ushort_t* __restrict__ Wqp, const ushort_t* __restrict__ Wkp,
    const ushort_t* __restrict__ Wvp,
    ushort_t* __restrict__ Qbf, ushort_t* __restrict__ Kpk,
    ushort_t* __restrict__ Vtp,
    const float* __restrict__ ln_q_g, const float* __restrict__ ln_q_b,
    const float* __restrict__ ln_kv_g, const float* __restrict__ ln_kv_b,
    const float* __restrict__ Hp, const float* __restrict__ bn_g,
    const float* __restrict__ bn_b, const float* __restrict__ W2,
    const float* __restrict__ b2, float* __restrict__ topo) {
  __shared__ ushort_t sA[64 * 128];   // 16 KB staging (proj paths)
  __shared__ ushort_t sT[64][264];    // 33 KB V transpose buffer (KV path)
  __shared__ float pp[26][28];        // topo halo buffer
  const int tid = threadIdx.x;

  if (blockIdx.x < 144) {
    // ================= KV path =================
    const int rowG = blockIdx.x * 64;
    {
      const int r = tid & 63, kg = tid >> 6;
      const int rr = rowG + r;
      const int b2v = rr / (K_N * HW_N);
      const int rem = rr - b2v * (K_N * HW_N);
      const int k = rem / HW_N;
      const int p = rem - k * HW_N;
      const float* s0 = F2 + (size_t)b2v * (C2_N * HW_N * K_N) + k + p * K_N;
      float rv[24];
#pragma unroll
      for (int i = 0; i < 24; i++)
        rv[i] = s0[(kg * 24 + i) * (HW_N * K_N)];
#pragma unroll
      for (int i = 0; i < 24; i += 2) {
        const int kk = kg * 24 + i;
        const unsigned pr =
            (unsigned)f2bf(rv[i]) | ((unsigned)f2bf(rv[i + 1]) << 16);
        ((unsigned*)sA)[r * 64 + (((kk >> 3) + r) & 15) * 4 + ((kk & 7) >> 1)] = pr;
      }
    }
    __syncthreads();
    const int wv = tid >> 6, lane = tid & 63;
    const int quad = lane >> 4, col = lane & 15;
    const int m = wv * 16 + col;
    bf16x8 xb[3];
#pragma unroll
    for (int ks = 0; ks < 3; ks++)
      xb[ks] = *(const bf16x8*)&sA[m * 128 + (((ks * 4 + quad) + m) & 15) * 8];

    const int mrow = rowG + m;
    const int bk = mrow / HW_N;
    const int p = mrow - bk * HW_N;
    const int pc = p >> 6, mm = p & 63;

    // ---- K ----
    {
      f32x4 acc[16];
#pragma unroll
      for (int nt = 0; nt < 16; nt++) {
        const ushort_t* wrow = Wkp + (nt * 16 + col) * 96 + quad * 8;
        f32x4 a = (f32x4){0.f, 0.f, 0.f, 0.f};
#pragma unroll
        for (int ks = 0; ks < 3; ks++) {
          bf16x8 wf = *(const bf16x8*)&wrow[ks * 32];
          a = __builtin_amdgcn_mfma_f32_16x16x32_bf16(wf, xb[ks], a, 0, 0, 0);
        }
        acc[nt] = a;
      }
      float s = 0.f;
#pragma unroll
      for (int nt = 0; nt < 16; nt++)
        s += acc[nt][0] + acc[nt][1] + acc[nt][2] + acc[nt][3];
      s += __shfl_xor(s, 16); s += __shfl_xor(s, 32);
      const float mean = s * (1.f / 256.f);
      float v = 0.f;
#pragma unroll
      for (int nt = 0; nt < 16; nt++)
#pragma unroll
        for (int r = 0; r < 4; r++) {
          const float d = acc[nt][r] - mean;
          v += d * d;
        }
      v += __shfl_xor(v, 16); v += __shfl_xor(v, 32);
      const float rstd = rsqrtf(v * (1.f / 256.f) + 1e-5f);
#pragma unroll
      for (int nt = 0; nt < 16; nt++) {
        const int n0 = nt * 16 + quad * 4;
        const float4 gv = *(const float4*)&ln_kv_g[n0];
        const float4 bv = *(const float4*)&ln_kv_b[n0];
        ushort4 o;
        o.x = f2bf(fmaf((acc[nt][0] - mean) * rstd, gv.x, bv.x));
        o.y = f2bf(fmaf((acc[nt][1] - mean) * rstd, gv.y, bv.y));
        o.z = f2bf(fmaf((acc[nt][2] - mean) * rstd, gv.z, bv.z));
        o.w = f2bf(fmaf((acc[nt][3] - mean) * rstd, gv.w, bv.w));
        const int h = nt >> 2;
        const int grp = ((nt & 3) * 2 + (quad >> 1)) ^ (mm & 7);
        ushort_t* dst = Kpk +
            ((size_t)((bk * 4 + h) * 9 + pc)) * 4096 +
            mm * 64 + grp * 8 + (quad & 1) * 4;
        *(ushort4*)dst = o;
      }
    }

    // ---- V ----
    {
      f32x4 acc[16];
#pragma unroll
      for (int nt = 0; nt < 16; nt++) {
        const ushort_t* wrow = Wvp + (nt * 16 + col) * 96 + quad * 8;
        f32x4 a = (f32x4){0.f, 0.f, 0.f, 0.f};
#pragma unroll
        for (int ks = 0; ks < 3; ks++) {
          bf16x8 wf = *(const bf16x8*)&wrow[ks * 32];
          a = __builtin_amdgcn_mfma_f32_16x16x32_bf16(wf, xb[ks], a, 0, 0, 0);
        }
        acc[nt] = a;
      }
      float s = 0.f;
#pragma unroll
      for (int nt = 0; nt < 16; nt++)
        s += acc[nt][0] + acc[nt][1] + acc[nt][2] + acc[nt][3];
      s += __shfl_xor(s, 16); s += __shfl_xor(s, 32);
      const float mean = s * (1.f / 256.f);
      float v = 0.f;
#pragma unroll
      for (int nt = 0; nt < 16; nt++)
#pragma unroll
        for (int r = 0; r < 4; r++) {
          const float d = acc[nt][r] - mean;
          v += d * d;
        }
      v += __shfl_xor(v, 16); v += __shfl_xor(v, 32);
      const float rstd = rsqrtf(v * (1.f / 256.f) + 1e-5f);
#pragma unroll
      for (int nt = 0; nt < 16; nt++) {
        const int n0 = nt * 16 + quad * 4;
        const float4 gv = *(const float4*)&ln_kv_g[n0];
        const float4 bv = *(const float4*)&ln_kv_b[n0];
        ushort4 o;
        o.x = f2bf(fmaf((acc[nt][0] - mean) * rstd, gv.x, bv.x));
        o.y = f2bf(fmaf((acc[nt][1] - mean) * rstd, gv.y, bv.y));
        o.z = f2bf(fmaf((acc[nt][2] - mean) * rstd, gv.z, bv.z));
        o.w = f2bf(fmaf((acc[nt][3] - mean) * rstd, gv.w, bv.w));
        *(ushort4*)&sT[m][n0] = o;
      }
    }
    __syncthreads();
    // transpose-pack phase
    const int hh = tid >> 6, d = tid & 63;
    __attribute__((aligned(16))) ushort_t tmp[64];
#pragma unroll
    for (int k = 0; k < 64; k++) {
      const int pk = (k & 32) + ((k & 4) << 2) + ((k & 24) >> 1) + (k & 3);
      tmp[k] = sT[pk][hh * 64 + d];
    }
    const int chunk = (bk * 4 + hh) * 9 + pc;
    uint4* dst = (uint4*)&Vtp[chunk * 4096 + d * 64];
    const int sw = d & 7;
#pragma unroll
    for (int gg = 0; gg < 8; gg++) dst[gg ^ sw] = ((const uint4*)tmp)[gg];
  } else if (blockIdx.x < 160) {
    // ================= topo tail (8 partials) =================
    const int bk = blockIdx.x - 144;
    const float inv = rsqrtf(1.0f + 1e-5f);
    float* ppf = &pp[0][0];
    for (int i = tid; i < 26 * 28; i += 256) ppf[i] = 0.f;
    const int p1 = tid + 256, p2v = tid + 512;   // p2v valid only tid<64
    float acc0 = b2[0], acc1 = b2[0], acc2 = b2[0];
#pragma unroll 2
    for (int t = 0; t < 64; t++) {
      const float w2t = W2[t];
      const float gt = bn_g[t] * inv;
      const float bt = bn_b[t];
      float v0 = 0.f, v1 = 0.f, v2 = 0.f;
#pragma unroll
      for (int c8 = 0; c8 < 8; c8++) {
        const float* hp = &Hp[((c8 * 16 + bk) * 64 + t) * HW_N];
        v0 += hp[tid];
        v1 += hp[p1];
        v2 += (p2v < HW_N) ? hp[p2v] : 0.f;
      }
      acc0 = fmaf(w2t, fmaxf(fmaf(gt, v0, bt), 0.f), acc0);
      acc1 = fmaf(w2t, fmaxf(fmaf(gt, v1, bt), 0.f), acc1);
      acc2 = fmaf(w2t, fmaxf(fmaf(gt, v2, bt), 0.f), acc2);
    }
    __syncthreads();   // zeros visible before interior writes
    pp[tid / 24 + 1][tid % 24 + 1] = acc0;
    pp[p1 / 24 + 1][p1 % 24 + 1] = acc1;
    if (p2v < HW_N) pp[p2v / 24 + 1][p2v % 24 + 1] = acc2;
    __syncthreads();
    const float accv[3] = {acc0, acc1, acc2};
#pragma unroll
    for (int pass = 0; pass < 3; pass++) {
      const int p = tid + pass * 256;
      if (p < HW_N) {
        const int yy = p / 24 + 1, xx = p % 24 + 1;
        float s = pp[yy-1][xx-1] + pp[yy-1][xx] + pp[yy-1][xx+1]
                + pp[yy][xx-1]                  + pp[yy][xx+1]
                + pp[yy+1][xx-1] + pp[yy+1][xx] + pp[yy+1][xx+1];
        topo[bk * HW_N + p] = accv[pass] + 0.5f * s;
      }
    }
  } else {
    // ================= Q path =================
    const int rowG = (blockIdx.x - 160) * 64;
    {
      const int r = tid & 63, kg = tid >> 6;
      const int rr = rowG + r;
      const int b2v = rr / (DZ_N * HW_N);
      const int rem = rr - b2v * (DZ_N * HW_N);
      const int o = rem / HW_N;
      const int p = rem - o * HW_N;
      const float* s0 = F3 + (size_t)b2v * (C3_N * DZ_N * HW_N) + o * HW_N + p;
      float rv[32];
#pragma unroll
      for (int i = 0; i < 32; i++)
        rv[i] = s0[(size_t)(kg * 32 + i) * (DZ_N * HW_N)];
#pragma unroll
      for (int i = 0; i < 32; i += 2) {
        const int k = kg * 32 + i;
        const unsigned pr =
            (unsigned)f2bf(rv[i]) | ((unsigned)f2bf(rv[i + 1]) << 16);
        ((unsigned*)sA)[r * 64 + (((k >> 3) + r) & 15) * 4 + ((k & 7) >> 1)] = pr;
      }
    }
    __syncthreads();
    const int wv = tid >> 6, lane = tid & 63;
    const int quad = lane >> 4, col = lane & 15;
    const int m = wv * 16 + col;
    bf16x8 xb[4];
#pragma unroll
    for (int ks = 0; ks < 4; ks++)
      xb[ks] = *(const bf16x8*)&sA[m * 128 + (((ks * 4 + quad) + m) & 15) * 8];
    f32x4 acc[16];
#pragma unroll
    for (int nt = 0; nt < 16; nt++) {
      const ushort_t* wrow = Wqp + (nt * 16 + col) * 128 + quad * 8;
      f32x4 a = (f32x4){0.f, 0.f, 0.f, 0.f};
#pragma unroll
      for (int ks = 0; ks < 4; ks++) {
        bf16x8 wf = *(const bf16x8*)&wrow[ks * 32];
        a = __builtin_amdgcn_mfma_f32_16x16x32_bf16(wf, xb[ks], a, 0, 0, 0);
      }
      acc[nt] = a;
    }
    const int mrow = rowG + m;
    float s = 0.f;
#pragma unroll
    for (int nt = 0; nt < 16; nt++)
      s += acc[nt][0] + acc[nt][1] + acc[nt][2] + acc[nt][3];
    s += __shfl_xor(s, 16); s += __shfl_xor(s, 32);
    const float mean = s * (1.f / 256.f);
    float v = 0.f;
#pragma unroll
    for (int nt = 0; nt < 16; nt++)
#pragma unroll
      for (int r = 0; r < 4; r++) {
        const float d = acc[nt][r] - mean;
        v += d * d;
      }
    v += __shfl_xor(v, 16); v += __shfl_xor(v, 32);
    const float rstd = rsqrtf(v * (1.f / 256.f) + 1e-5f);
    // fold attn scale (1/sqrt(HD)) * log2(e) into Q
    const float QS = 0.18033688f;   // 0.125 * 1.44269504
    ushort_t* dst = Qbf + (size_t)mrow * E_N;
#pragma unroll
    for (int nt = 0; nt < 16; nt++) {
      const int n0 = nt * 16 + quad * 4;
      const float4 gv = *(const float4*)&ln_q_g[n0];
      const float4 bv = *(const float4*)&ln_q_b[n0];
      ushort4 o;
      o.x = f2bf(QS * fmaf((acc[nt][0] - mean) * rstd, gv.x, bv.x));
      o.y = f2bf(QS * fmaf((acc[nt][1] - mean) * rstd, gv.y, bv.y));
      o.z = f2bf(QS * fmaf((acc[nt][2] - mean) * rstd, gv.z, bv.z));
      o.w = f2bf(QS * fmaf((acc[nt][3] - mean) * rstd, gv.w, bv.w));
      *(ushort4*)&dst[n0] = o;
    }
  }
}

// ---------------------------------------------------------------------------
// Flash-style slab cross attention (R5-EXACT structure — the measured local
// optimum at 87.2-89.0 us across 7 runs). Untouched.
// ---------------------------------------------------------------------------
__global__ __launch_bounds__(256) void attn_kernel(
    const ushort_t* __restrict__ Qbf, const ushort_t* __restrict__ Kpk,
    const ushort_t* __restrict__ Vtp, const float* __restrict__ topo,
    const float* __restrict__ lamp, const int* __restrict__ D0p,
    const int* __restrict__ slabp, ushort_t* __restrict__ Obf) {
  const int bid = blockIdx.x;
  const int hb = bid & 7;
  const int h = hb & 3, b = hb >> 2;
  const int zp = (bid >> 3) & 15;
  const int pb = bid >> 7;                 // 0..8
  const int p0 = pb * 64;
  const int tid = threadIdx.x;
  const int w = tid >> 6, lane = tid & 63;
  const int quad = lane >> 4, col = lane & 15;
  const int z = zp * 2 + (w >> 1);
  const int th = w & 1;

  const float LOG2E = 1.44269504f;
  const float lam2 = lamp[0] * LOG2E;
  const int D0 = D0p[0], slab = slabp[0];
  const float step = (float)(D0 - 1) / (float)(DZ_N - 1);

  int kkw, kka, kkb;
  {
    int z0 = (int)floorf(fmaf((float)z, step, 0.5f));
    int kv = z0 / slab;
    kkw = kv < 0 ? 0 : (kv > K_N - 1 ? K_N - 1 : kv);
    int z0a = (int)floorf(fmaf((float)(zp * 2), step, 0.5f));
    int z0b = (int)floorf(fmaf((float)(zp * 2 + 1), step, 0.5f));
    int ka = z0a / slab; ka = ka < 0 ? 0 : (ka > K_N - 1 ? K_N - 1 : ka);
    int kb = z0b / slab; kb = kb < 0 ? 0 : (kb > K_N - 1 ? K_N - 1 : kb);
    kka = ka < kb ? ka : kb;
    kkb = ka < kb ? kb : ka;
  }
  const int c_lo = (kka - 1) < 0 ? 0 : (kka - 1);
  const int c_hi = (kkb + 1) > (K_N - 1) ? (K_N - 1) : (kkb + 1);

  __shared__ ushort_t sKV[2][8192];    // dbuf: [buf][ K 8KB | V 8KB ] = 32 KB

  auto issue_fill = [&](int buf, int c, int pc) {
    const size_t cb = ((size_t)(((b * K_N + c) * 4 + h) * 9) + pc) * 4096;
#pragma unroll
    for (int j = 0; j < 4; j++) {
      const int seg = (w << 2) + j;    // 0..15
      const ushort_t* gsrc = (w < 2)
          ? (Kpk + cb + seg * 512 + lane * 8)
          : (Vtp + cb + (seg - 8) * 512 + lane * 8);
      ushort_t* ldst = &sKV[buf][seg * 512];
      __builtin_amdgcn_global_load_lds(
          (const __attribute__((address_space(1))) void*)gsrc,
          (__attribute__((address_space(3))) void*)ldst, 16, 0, 0);
    }
  };

  // ones A-frag for lsum-via-MFMA (layout-invariant: all elements 1.0bf16)
  union { ushort_t u[8]; bf16x8 v; } uo;
#pragma unroll
  for (int i = 0; i < 8; i++) uo.u[i] = 0x3F80;
  const bf16x8 vone = uo.v;

  // Q B-frags (2 tiles)
  bf16x8 bq[2][2];
  const int qrow0 = (b * DZ_N + z) * HW_N + p0 + th * 32;
#pragma unroll
  for (int t = 0; t < 2; t++) {
    const ushort_t* qp = &Qbf[(qrow0 + t * 16 + col) * E_N + h * 64 + quad * 8];
    bq[t][0] = *(const bf16x8*)qp;
    bq[t][1] = *(const bf16x8*)(qp + 32);
  }

  f32x4 oacc[2][4];
#pragma unroll
  for (int t = 0; t < 2; t++)
#pragma unroll
    for (int dt = 0; dt < 4; dt++) oacc[t][dt] = (f32x4){0.f, 0.f, 0.f, 0.f};
  f32x4 lacc[2];
  lacc[0] = (f32x4){0.f, 0.f, 0.f, 0.f};
  lacc[1] = (f32x4){0.f, 0.f, 0.f, 0.f};

  const int s7 = col & 7;
  const int o1 = (quad ^ s7) * 8;
  const int o2 = ((quad + 4) ^ s7) * 8;

  int buf = 0;
  issue_fill(0, c_lo, 0);   // prologue

  for (int c = c_lo; c <= c_hi; c++) {
    const bool act = (c >= kkw - 1) && (c <= kkw + 1);
    const float biasE2 = ((c == kkw) ? -20.0f : -20.5f) * LOG2E;
    const f32x4 bias4 = (f32x4){biasE2, biasE2, biasE2, biasE2};
    const float* topoc = &topo[(b * K_N + c) * HW_N + p0];
#pragma unroll 1
    for (int pc = 0; pc < 9; pc++) {
      __syncthreads();   // drains in-flight fill; all waves arrive
      {
        int pc2 = pc + 1, c2 = c;
        if (pc2 == 9) { pc2 = 0; c2 = c + 1; }
        if (c2 <= c_hi) issue_fill(buf ^ 1, c2, pc2);
      }
      const ushort_t* sKb = &sKV[buf][0];
      const ushort_t* sVb = &sKV[buf][4096];
      buf ^= 1;
      if (!act) continue;

      bf16x8 ka[4][2];
#pragma unroll
      for (int kt = 0; kt < 4; kt++) {
        const ushort_t* kr = sKb + (kt * 16 + col) * 64;
        ka[kt][0] = *(const bf16x8*)(kr + o1);
        ka[kt][1] = *(const bf16x8*)(kr + o2);
      }

      bf16x8 pfrag[2][2];
#pragma unroll
      for (int t = 0; t < 2; t++) {
        f32x4 sv[4];
#pragma unroll
        for (int kt = 0; kt < 4; kt++) {
          // C-operand carries scale*logit + bias: Q was pre-scaled, C=bias4.
          f32x4 acc = __builtin_amdgcn_mfma_f32_16x16x32_bf16(
              ka[kt][0], bq[t][0], bias4, 0, 0, 0);
          acc = __builtin_amdgcn_mfma_f32_16x16x32_bf16(
              ka[kt][1], bq[t][1], acc, 0, 0, 0);
          sv[kt] = acc;
        }
        float xv[4][4];
#pragma unroll
        for (int kt = 0; kt < 4; kt++)
#pragma unroll
          for (int r = 0; r < 4; r++)
            xv[kt][r] = sv[kt][r];
        if (pc == pb) {
          const int ctt = th * 2 + t;
          const float tv2 = lam2 * topoc[th * 32 + t * 16 + col];
          const bool qok = ((col >> 2) == quad);
#pragma unroll
          for (int kt = 0; kt < 4; kt++)
#pragma unroll
            for (int r = 0; r < 4; r++)
              xv[kt][r] += (qok && kt == ctt && (col & 3) == r) ? tv2 : 0.f;
        }
        float ev[4][4];
#pragma unroll
        for (int kt = 0; kt < 4; kt++)
#pragma unroll
          for (int r = 0; r < 4; r++)
            ev[kt][r] = __builtin_amdgcn_exp2f(xv[kt][r]);
#pragma unroll
        for (int f = 0; f < 2; f++) {
          union { uint4 u; bf16x8 v; } pk;
          pk.u.x = __builtin_amdgcn_perm(__float_as_uint(ev[f*2][1]),
                                         __float_as_uint(ev[f*2][0]), 0x07060302u);
          pk.u.y = __builtin_amdgcn_perm(__float_as_uint(ev[f*2][3]),
                                         __float_as_uint(ev[f*2][2]), 0x07060302u);
          pk.u.z = __builtin_amdgcn_perm(__float_as_uint(ev[f*2+1][1]),
                                         __float_as_uint(ev[f*2+1][0]), 0x07060302u);
          pk.u.w = __builtin_amdgcn_perm(__float_as_uint(ev[f*2+1][3]),
                                         __float_as_uint(ev[f*2+1][2]), 0x07060302u);
          pfrag[t][f] = pk.v;
        }
        // lsum on the MFMA pipe: ones-A column-sums of P (all D rows equal).
        lacc[t] = __builtin_amdgcn_mfma_f32_16x16x32_bf16(
            vone, pfrag[t][0], lacc[t], 0, 0, 0);
        lacc[t] = __builtin_amdgcn_mfma_f32_16x16x32_bf16(
            vone, pfrag[t][1], lacc[t], 0, 0, 0);
      }

#pragma unroll
      for (int dt = 0; dt < 4; dt++) {
        const ushort_t* vr = sVb + (dt * 16 + col) * 64;
        bf16x8 va0 = *(const bf16x8*)(vr + o1);
        bf16x8 va1 = *(const bf16x8*)(vr + o2);
#pragma unroll
        for (int t = 0; t < 2; t++) {
          oacc[t][dt] = __builtin_amdgcn_mfma_f32_16x16x32_bf16(va0, pfrag[t][0], oacc[t][dt], 0, 0, 0);
          oacc[t][dt] = __builtin_amdgcn_mfma_f32_16x16x32_bf16(va1, pfrag[t][1], oacc[t][dt], 0, 0, 0);
        }
      }
    }
  }

  // epilogue: lacc already holds full row-sum (no cross-quad reduce needed)
#pragma unroll
  for (int t = 0; t < 2; t++) {
    const float invl = 1.f / lacc[t][0];
    const int row = qrow0 + t * 16 + col;
    ushort_t* orow = &Obf[(size_t)row * E_N + h * 64];
#pragma unroll
    for (int dt = 0; dt < 4; dt++) {
      ushort4 o;
      o.x = f2bf(oacc[t][dt][0] * invl);
      o.y = f2bf(oacc[t][dt][1] * invl);
      o.z = f2bf(oacc[t][dt][2] * invl);
      o.w = f2bf(oacc[t][dt][3] * invl);
      *(ushort4*)&orow[dt * 16 + quad * 4] = o;
    }
  }
}

// ---------------------------------------------------------------------------
// Output projection (MFMA) + residual. Residual unroll x8.
// ---------------------------------------------------------------------------
__global__ __launch_bounds__(256) void out_proj_mfma(
    const ushort_t* __restrict__ Obf, const ushort_t* __restrict__ Wpp,
    const float* __restrict__ F3, float* __restrict__ outp) {
  __shared__ float sOut[64][129];
  const int tid = threadIdx.x;
  const int rowG = blockIdx.x * 64;
  const int wv = tid >> 6, lane = tid & 63;
  const int quad = lane >> 4, col = lane & 15;

  const ushort_t* xrow = &Obf[(size_t)(rowG + wv * 16 + col) * E_N + quad * 8];
  bf16x8 af[8];
#pragma unroll
  for (int ks = 0; ks < 8; ks++) af[ks] = *(const bf16x8*)&xrow[ks * 32];

#pragma unroll
  for (int nt = 0; nt < 8; nt++) {
    const ushort_t* wrow = &Wpp[(nt * 16 + col) * 256 + quad * 8];
    f32x4 a = (f32x4){0.f, 0.f, 0.f, 0.f};
#pragma unroll
    for (int ks = 0; ks < 8; ks++) {
      bf16x8 wf = *(const bf16x8*)&wrow[ks * 32];
      a = __builtin_amdgcn_mfma_f32_16x16x32_bf16(af[ks], wf, a, 0, 0, 0);
    }
#pragma unroll
    for (int r = 0; r < 4; r++)
      sOut[wv * 16 + quad * 4 + r][nt * 16 + col] = a[r];
  }
  __syncthreads();
  const int b = rowG / (DZ_N * HW_N);
  const int rem = rowG - b * DZ_N * HW_N;
  const int z = rem / HW_N;
  const int pp0 = rem - z * HW_N;
  const int pl = tid & 63, cg = tid >> 6;
#pragma unroll 8
  for (int c = cg * 32; c < cg * 32 + 32; c++) {
    const int gidx = ((b * C3_N + c) * DZ_N + z) * HW_N + pp0 + pl;
    outp[gidx] = F3[gidx] + sOut[pl][c];
  }
}

// ---------------------------------------------------------------------------
extern "C" void kernel_launch(void* const* d_in, const int* in_sizes, int n_in,
                              void* d_out, int out_size, void* d_ws, size_t ws_size,
                              hipStream_t stream) {
  (void)in_sizes; (void)n_in; (void)out_size; (void)ws_size;
  const float* F3      = (const float*)d_in[0];
  const float* F2      = (const float*)d_in[1];
  const float* Wq      = (const float*)d_in[2];
  const float* Wk      = (const float*)d_in[3];
  const float* Wv      = (const float*)d_in[4];
  const float* Wp      = (const float*)d_in[5];
  const float* ln_q_g  = (const float*)d_in[6];
  const float* ln_q_b  = (const float*)d_in[7];
  const float* ln_kv_g = (const float*)d_in[8];
  const float* ln_kv_b = (const float*)d_in[9];
  const float* conv1_w = (const float*)d_in[10];
  const float* bn_g    = (const float*)d_in[11];
  const float* bn_b    = (const float*)d_in[12];
  const float* conv2_w = (const float*)d_in[13];
  const float* conv2_b = (const float*)d_in[14];
  const float* lam     = (const float*)d_in[15];
  const int*   D0      = (const int*)d_in[16];
  const int*   slab    = (const int*)d_in[17];
  float* out = (float*)d_out;

  char* ws = (char*)d_ws;
  size_t off = 0;
  auto alloc = [&](size_t bytes) {
    void* p = ws + off;
    off += (bytes + 255) & ~(size_t)255;
    return p;
  };
  const int QROWS = B_N * DZ_N * HW_N;   // 36864
  const int KVROWS = B_N * K_N * HW_N;   // 9216
  ushort_t* Qbf = (ushort_t*)alloc((size_t)QROWS * E_N * 2);
  ushort_t* Kpk = (ushort_t*)alloc((size_t)KVROWS * E_N * 2);
  ushort_t* Vtp = (ushort_t*)alloc((size_t)KVROWS * E_N * 2);
  ushort_t* Obf = (ushort_t*)alloc((size_t)QROWS * E_N * 2);  // aliases Hp
  float* topo = (float*)alloc((size_t)B_N * K_N * HW_N * 4);
  ushort_t* Wqp = (ushort_t*)alloc(256 * 128 * 2);
  ushort_t* Wkp = (ushort_t*)alloc(256 * 96 * 2);
  ushort_t* Wvp = (ushort_t*)alloc(256 * 96 * 2);
  ushort_t* Wpp = (ushort_t*)alloc(128 * 256 * 2);
  float* Hp = (float*)Obf;   // 8*16*64*576*4 = 18.87 MB == Obf; dead b4 attn

  // 1) fused conv (512 blocks, 2/CU) + weight packing
  pre_conv_pack<<<1408, 384, 0, stream>>>(
      F2, conv1_w, Hp, Wq, Wk, Wv, Wp, Wqp, Wkp, Wvp, Wpp);
  // 2) fused Q + KV projections + topo tail (batched staging loads)
  proj_all<<<736, 256, 0, stream>>>(
      F3, F2, Wqp, Wkp, Wvp, Qbf, Kpk, Vtp,
      ln_q_g, ln_q_b, ln_kv_g, ln_kv_b,
      Hp, bn_g, bn_b, conv2_w, conv2_b, topo);
  // 3) attention -> bf16 O  (4-wave blocks, 2 z per block)
  attn_kernel<<<1152, 256, 0, stream>>>(
      Qbf, Kpk, Vtp, topo, lam, D0, slab, Obf);
  // 4) output projection (MFMA) + residual
  out_proj_mfma<<<QROWS / 64, 256, 0, stream>>>(Obf, Wpp, F3, out);
}

// Round 15
// 280.289 us; speedup vs baseline: 1.0176x; 1.0176x over previous
//
#include <hip/hip_runtime.h>

typedef float f32x4 __attribute__((ext_vector_type(4)));
typedef __bf16 bf16x8 __attribute__((ext_vector_type(8)));
typedef unsigned short ushort_t;

#define DEV_INLINE __device__ __forceinline__

constexpr int B_N  = 2;
constexpr int C3_N = 128;
constexpr int C2_N = 96;
constexpr int DZ_N = 32;
constexpr int H_N  = 24;
constexpr int W_N  = 24;
constexpr int K_N  = 8;
constexpr int E_N  = 256;
constexpr int HW_N = 576;

DEV_INLINE unsigned short f2bf(float x) {
  union { __bf16 b; unsigned short u; } v;
  v.b = (__bf16)x;
  return v.u;
}

// ---------------------------------------------------------------------------
// Fused: topo 3x3 conv (blocks 0..511) U weight packing (blocks 512..1407).
// Conv split 8 channel-chunks (2/CU) — R13, kept (small real gain).
// ---------------------------------------------------------------------------
__global__ __launch_bounds__(384) void pre_conv_pack(
    const float* __restrict__ F2, const float* __restrict__ W1,
    float* __restrict__ Hp,
    const float* __restrict__ Wq, const float* __restrict__ Wk,
    const float* __restrict__ Wv, const float* __restrict__ Wp,
    ushort_t* __restrict__ Wqp, ushort_t* __restrict__ Wkp,
    ushort_t* __restrict__ Wvp, ushort_t* __restrict__ Wpp) {
  __shared__ float simg[6][26][28];
  __shared__ float sw[16 * 97];
  const int bid0 = blockIdx.x;
  if (bid0 >= 512) {
    // ---- pack branch ----
    const int bblk = bid0 - 512, t = threadIdx.x;
    if (t < 256) {
      if (bblk < 256) {
        if (t < 128) Wqp[bblk * 128 + t] = f2bf(Wq[t * 256 + bblk]);
      } else if (bblk < 512) {
        const int n = bblk - 256;
        if (t < 96) Wkp[n * 96 + t] = f2bf(Wk[t * 256 + n]);
      } else if (bblk < 768) {
        const int n = bblk - 512;
        if (t < 96) Wvp[n * 96 + t] = f2bf(Wv[t * 256 + n]);
      } else {
        const int c = bblk - 768;
        Wpp[c * 256 + t] = f2bf(Wp[t * 128 + c]);
      }
    }
    return;
  }
  // ---- conv branch: cc(8) x tg(4) x bk(16) = 512 blocks ----
  const int bid = bid0;
  const int cc = bid & 7;            // 8 chunks of 12 channels
  const int tg = (bid >> 3) & 3;
  const int bk = bid >> 5;           // 0..15 = b*8 + k
  const int b = bk >> 3, k = bk & 7;
  const int tid = threadIdx.x;
  const int y = tid >> 4;            // 0..23
  const int tq = tid & 15;           // 0..15

  float acc[24];
#pragma unroll
  for (int i = 0; i < 24; i++) acc[i] = 0.f;

  float* simgf = &simg[0][0][0];
  for (int i = tid; i < 6 * 26 * 28; i += 384) simgf[i] = 0.f;
  __syncthreads();

  for (int ch = 0; ch < 2; ch++) {
    if (ch) __syncthreads();
    const int c0 = cc * 12 + ch * 6;
    for (int i = tid; i < 6 * 24 * 24; i += 384) {
      int c = i / 576, p = i - c * 576;
      int yy = p / 24, xx = p - yy * 24;
      simg[c][yy + 1][xx + 1] =
          F2[(((b * C2_N + c0 + c) * H_N + yy) * W_N + xx) * K_N + k];
    }
    for (int i = tid; i < 16 * 54; i += 384) {
      int t2 = i / 54, rest = i - t2 * 54;
      int c = rest / 9, q = rest - c * 9;
      sw[t2 * 97 + c * 12 + q] =
          W1[(tg * 16 + t2) * (C2_N * 9) + (c0 + c) * 9 + q];
    }
    __syncthreads();
#pragma unroll 1
    for (int c = 0; c < 6; c++) {
      float w[9];
#pragma unroll
      for (int q = 0; q < 9; q++) w[q] = sw[tq * 97 + c * 12 + q];
#pragma unroll
      for (int dy = 0; dy < 3; dy++) {
        float r[28];   // full padded row: cols 26,27 are zero pad (unused)
#pragma unroll
        for (int g = 0; g < 7; g++)
          *(float4*)&r[g * 4] = *(const float4*)&simg[c][y + dy][g * 4];
#pragma unroll
        for (int dx = 0; dx < 3; dx++) {
          float wv = w[dy * 3 + dx];
#pragma unroll
          for (int xx = 0; xx < 24; xx++)
            acc[xx] = fmaf(wv, r[xx + dx], acc[xx]);
        }
      }
    }
  }
  const int t = tg * 16 + tq;
  float* dst = &Hp[((cc * 16 + bk) * 64 + t) * HW_N + y * 24];
#pragma unroll
  for (int xx = 0; xx < 24; xx++) dst[xx] = acc[xx];
}

// ---------------------------------------------------------------------------
// Fused projections + topo tail (R13-exact):
//   blocks 0..143   = K+V projection path
//   blocks 144..159 = topo tail (8 partials)
//   blocks 160..735 = Q projection path
// ---------------------------------------------------------------------------
__global__ __launch_bounds__(256) void proj_all(
    const float* __restrict__ F3, const float* __restrict__ F2,
    const ushort_t* __restrict__ Wqp, const ushort_t* __restrict__ Wkp,
    const ushort_t* __restrict__ Wvp,
    ushort_t* __restrict__ Qbf, ushort_t* __restrict__ Kpk,
    ushort_t* __restrict__ Vtp,
    const float* __restrict__ ln_q_g, const float* __restrict__ ln_q_b,
    const float* __restrict__ ln_kv_g, const float* __restrict__ ln_kv_b,
    const float* __restrict__ Hp, const float* __restrict__ bn_g,
    const float* __restrict__ bn_b, const float* __restrict__ W2,
    const float* __restrict__ b2, float* __restrict__ topo) {
  __shared__ ushort_t sA[64 * 128];   // 16 KB staging (proj paths)
  __shared__ ushort_t sT[64][264];    // 33 KB V transpose buffer (KV path)
  __shared__ float pp[26][28];        // topo halo buffer
  const int tid = threadIdx.x;

  if (blockIdx.x < 144) {
    // ================= KV path =================
    const int rowG = blockIdx.x * 64;
    {
      const int r = tid & 63, kg = tid >> 6;
      const int rr = rowG + r;
      const int b2v = rr / (K_N * HW_N);
      const int rem = rr - b2v * (K_N * HW_N);
      const int k = rem / HW_N;
      const int p = rem - k * HW_N;
      const float* s0 = F2 + (size_t)b2v * (C2_N * HW_N * K_N) + k + p * K_N;
#pragma unroll
      for (int i = 0; i < 24; i += 2) {
        const int kk = kg * 24 + i;
        const float x0 = s0[kk * (HW_N * K_N)];
        const float x1 = s0[(kk + 1) * (HW_N * K_N)];
        const unsigned pr = (unsigned)f2bf(x0) | ((unsigned)f2bf(x1) << 16);
        ((unsigned*)sA)[r * 64 + (((kk >> 3) + r) & 15) * 4 + ((kk & 7) >> 1)] = pr;
      }
    }
    __syncthreads();
    const int wv = tid >> 6, lane = tid & 63;
    const int quad = lane >> 4, col = lane & 15;
    const int m = wv * 16 + col;
    bf16x8 xb[3];
#pragma unroll
    for (int ks = 0; ks < 3; ks++)
      xb[ks] = *(const bf16x8*)&sA[m * 128 + (((ks * 4 + quad) + m) & 15) * 8];

    const int mrow = rowG + m;
    const int bk = mrow / HW_N;
    const int p = mrow - bk * HW_N;
    const int pc = p >> 6, mm = p & 63;

    // ---- K ----
    {
      f32x4 acc[16];
#pragma unroll
      for (int nt = 0; nt < 16; nt++) {
        const ushort_t* wrow = Wkp + (nt * 16 + col) * 96 + quad * 8;
        f32x4 a = (f32x4){0.f, 0.f, 0.f, 0.f};
#pragma unroll
        for (int ks = 0; ks < 3; ks++) {
          bf16x8 wf = *(const bf16x8*)&wrow[ks * 32];
          a = __builtin_amdgcn_mfma_f32_16x16x32_bf16(wf, xb[ks], a, 0, 0, 0);
        }
        acc[nt] = a;
      }
      float s = 0.f;
#pragma unroll
      for (int nt = 0; nt < 16; nt++)
        s += acc[nt][0] + acc[nt][1] + acc[nt][2] + acc[nt][3];
      s += __shfl_xor(s, 16); s += __shfl_xor(s, 32);
      const float mean = s * (1.f / 256.f);
      float v = 0.f;
#pragma unroll
      for (int nt = 0; nt < 16; nt++)
#pragma unroll
        for (int r = 0; r < 4; r++) {
          const float d = acc[nt][r] - mean;
          v += d * d;
        }
      v += __shfl_xor(v, 16); v += __shfl_xor(v, 32);
      const float rstd = rsqrtf(v * (1.f / 256.f) + 1e-5f);
#pragma unroll
      for (int nt = 0; nt < 16; nt++) {
        const int n0 = nt * 16 + quad * 4;
        const float4 gv = *(const float4*)&ln_kv_g[n0];
        const float4 bv = *(const float4*)&ln_kv_b[n0];
        ushort4 o;
        o.x = f2bf(fmaf((acc[nt][0] - mean) * rstd, gv.x, bv.x));
        o.y = f2bf(fmaf((acc[nt][1] - mean) * rstd, gv.y, bv.y));
        o.z = f2bf(fmaf((acc[nt][2] - mean) * rstd, gv.z, bv.z));
        o.w = f2bf(fmaf((acc[nt][3] - mean) * rstd, gv.w, bv.w));
        const int h = nt >> 2;
        const int grp = ((nt & 3) * 2 + (quad >> 1)) ^ (mm & 7);
        ushort_t* dst = Kpk +
            ((size_t)((bk * 4 + h) * 9 + pc)) * 4096 +
            mm * 64 + grp * 8 + (quad & 1) * 4;
        *(ushort4*)dst = o;
      }
    }

    // ---- V ----
    {
      f32x4 acc[16];
#pragma unroll
      for (int nt = 0; nt < 16; nt++) {
        const ushort_t* wrow = Wvp + (nt * 16 + col) * 96 + quad * 8;
        f32x4 a = (f32x4){0.f, 0.f, 0.f, 0.f};
#pragma unroll
        for (int ks = 0; ks < 3; ks++) {
          bf16x8 wf = *(const bf16x8*)&wrow[ks * 32];
          a = __builtin_amdgcn_mfma_f32_16x16x32_bf16(wf, xb[ks], a, 0, 0, 0);
        }
        acc[nt] = a;
      }
      float s = 0.f;
#pragma unroll
      for (int nt = 0; nt < 16; nt++)
        s += acc[nt][0] + acc[nt][1] + acc[nt][2] + acc[nt][3];
      s += __shfl_xor(s, 16); s += __shfl_xor(s, 32);
      const float mean = s * (1.f / 256.f);
      float v = 0.f;
#pragma unroll
      for (int nt = 0; nt < 16; nt++)
#pragma unroll
        for (int r = 0; r < 4; r++) {
          const float d = acc[nt][r] - mean;
          v += d * d;
        }
      v += __shfl_xor(v, 16); v += __shfl_xor(v, 32);
      const float rstd = rsqrtf(v * (1.f / 256.f) + 1e-5f);
#pragma unroll
      for (int nt = 0; nt < 16; nt++) {
        const int n0 = nt * 16 + quad * 4;
        const float4 gv = *(const float4*)&ln_kv_g[n0];
        const float4 bv = *(const float4*)&ln_kv_b[n0];
        ushort4 o;
        o.x = f2bf(fmaf((acc[nt][0] - mean) * rstd, gv.x, bv.x));
        o.y = f2bf(fmaf((acc[nt][1] - mean) * rstd, gv.y, bv.y));
        o.z = f2bf(fmaf((acc[nt][2] - mean) * rstd, gv.z, bv.z));
        o.w = f2bf(fmaf((acc[nt][3] - mean) * rstd, gv.w, bv.w));
        *(ushort4*)&sT[m][n0] = o;
      }
    }
    __syncthreads();
    // transpose-pack phase
    const int hh = tid >> 6, d = tid & 63;
    __attribute__((aligned(16))) ushort_t tmp[64];
#pragma unroll
    for (int k = 0; k < 64; k++) {
      const int pk = (k & 32) + ((k & 4) << 2) + ((k & 24) >> 1) + (k & 3);
      tmp[k] = sT[pk][hh * 64 + d];
    }
    const int chunk = (bk * 4 + hh) * 9 + pc;
    uint4* dst = (uint4*)&Vtp[chunk * 4096 + d * 64];
    const int sw = d & 7;
#pragma unroll
    for (int gg = 0; gg < 8; gg++) dst[gg ^ sw] = ((const uint4*)tmp)[gg];
  } else if (blockIdx.x < 160) {
    // ================= topo tail (8 partials) =================
    const int bk = blockIdx.x - 144;
    const float inv = rsqrtf(1.0f + 1e-5f);
    float* ppf = &pp[0][0];
    for (int i = tid; i < 26 * 28; i += 256) ppf[i] = 0.f;
    const int p1 = tid + 256, p2v = tid + 512;   // p2v valid only tid<64
    float acc0 = b2[0], acc1 = b2[0], acc2 = b2[0];
#pragma unroll 2
    for (int t = 0; t < 64; t++) {
      const float w2t = W2[t];
      const float gt = bn_g[t] * inv;
      const float bt = bn_b[t];
      float v0 = 0.f, v1 = 0.f, v2 = 0.f;
#pragma unroll
      for (int c8 = 0; c8 < 8; c8++) {
        const float* hp = &Hp[((c8 * 16 + bk) * 64 + t) * HW_N];
        v0 += hp[tid];
        v1 += hp[p1];
        v2 += (p2v < HW_N) ? hp[p2v] : 0.f;
      }
      acc0 = fmaf(w2t, fmaxf(fmaf(gt, v0, bt), 0.f), acc0);
      acc1 = fmaf(w2t, fmaxf(fmaf(gt, v1, bt), 0.f), acc1);
      acc2 = fmaf(w2t, fmaxf(fmaf(gt, v2, bt), 0.f), acc2);
    }
    __syncthreads();   // zeros visible before interior writes
    pp[tid / 24 + 1][tid % 24 + 1] = acc0;
    pp[p1 / 24 + 1][p1 % 24 + 1] = acc1;
    if (p2v < HW_N) pp[p2v / 24 + 1][p2v % 24 + 1] = acc2;
    __syncthreads();
    const float accv[3] = {acc0, acc1, acc2};
#pragma unroll
    for (int pass = 0; pass < 3; pass++) {
      const int p = tid + pass * 256;
      if (p < HW_N) {
        const int yy = p / 24 + 1, xx = p % 24 + 1;
        float s = pp[yy-1][xx-1] + pp[yy-1][xx] + pp[yy-1][xx+1]
                + pp[yy][xx-1]                  + pp[yy][xx+1]
                + pp[yy+1][xx-1] + pp[yy+1][xx] + pp[yy+1][xx+1];
        topo[bk * HW_N + p] = accv[pass] + 0.5f * s;
      }
    }
  } else {
    // ================= Q path =================
    const int rowG = (blockIdx.x - 160) * 64;
    {
      const int r = tid & 63, kg = tid >> 6;
      const int rr = rowG + r;
      const int b2v = rr / (DZ_N * HW_N);
      const int rem = rr - b2v * (DZ_N * HW_N);
      const int o = rem / HW_N;
      const int p = rem - o * HW_N;
      const float* s0 = F3 + (size_t)b2v * (C3_N * DZ_N * HW_N) + o * HW_N + p;
#pragma unroll
      for (int i = 0; i < 32; i += 2) {
        const int k = kg * 32 + i;
        const float x0 = s0[(size_t)k * (DZ_N * HW_N)];
        const float x1 = s0[(size_t)(k + 1) * (DZ_N * HW_N)];
        const unsigned pr = (unsigned)f2bf(x0) | ((unsigned)f2bf(x1) << 16);
        ((unsigned*)sA)[r * 64 + (((k >> 3) + r) & 15) * 4 + ((k & 7) >> 1)] = pr;
      }
    }
    __syncthreads();
    const int wv = tid >> 6, lane = tid & 63;
    const int quad = lane >> 4, col = lane & 15;
    const int m = wv * 16 + col;
    bf16x8 xb[4];
#pragma unroll
    for (int ks = 0; ks < 4; ks++)
      xb[ks] = *(const bf16x8*)&sA[m * 128 + (((ks * 4 + quad) + m) & 15) * 8];
    f32x4 acc[16];
#pragma unroll
    for (int nt = 0; nt < 16; nt++) {
      const ushort_t* wrow = Wqp + (nt * 16 + col) * 128 + quad * 8;
      f32x4 a = (f32x4){0.f, 0.f, 0.f, 0.f};
#pragma unroll
      for (int ks = 0; ks < 4; ks++) {
        bf16x8 wf = *(const bf16x8*)&wrow[ks * 32];
        a = __builtin_amdgcn_mfma_f32_16x16x32_bf16(wf, xb[ks], a, 0, 0, 0);
      }
      acc[nt] = a;
    }
    const int mrow = rowG + m;
    float s = 0.f;
#pragma unroll
    for (int nt = 0; nt < 16; nt++)
      s += acc[nt][0] + acc[nt][1] + acc[nt][2] + acc[nt][3];
    s += __shfl_xor(s, 16); s += __shfl_xor(s, 32);
    const float mean = s * (1.f / 256.f);
    float v = 0.f;
#pragma unroll
    for (int nt = 0; nt < 16; nt++)
#pragma unroll
      for (int r = 0; r < 4; r++) {
        const float d = acc[nt][r] - mean;
        v += d * d;
      }
    v += __shfl_xor(v, 16); v += __shfl_xor(v, 32);
    const float rstd = rsqrtf(v * (1.f / 256.f) + 1e-5f);
    // fold attn scale (1/sqrt(HD)) * log2(e) into Q
    const float QS = 0.18033688f;   // 0.125 * 1.44269504
    ushort_t* dst = Qbf + (size_t)mrow * E_N;
#pragma unroll
    for (int nt = 0; nt < 16; nt++) {
      const int n0 = nt * 16 + quad * 4;
      const float4 gv = *(const float4*)&ln_q_g[n0];
      const float4 bv = *(const float4*)&ln_q_b[n0];
      ushort4 o;
      o.x = f2bf(QS * fmaf((acc[nt][0] - mean) * rstd, gv.x, bv.x));
      o.y = f2bf(QS * fmaf((acc[nt][1] - mean) * rstd, gv.y, bv.y));
      o.z = f2bf(QS * fmaf((acc[nt][2] - mean) * rstd, gv.z, bv.z));
      o.w = f2bf(QS * fmaf((acc[nt][3] - mean) * rstd, gv.w, bv.w));
      *(ushort4*)&dst[n0] = o;
    }
  }
}

// ---------------------------------------------------------------------------
// Flash-style slab cross attention (R5-EXACT structure — the measured local
// optimum at 87.2-89.7 us across 8 runs). Untouched.
// ---------------------------------------------------------------------------
__global__ __launch_bounds__(256) void attn_kernel(
    const ushort_t* __restrict__ Qbf, const ushort_t* __restrict__ Kpk,
    const ushort_t* __restrict__ Vtp, const float* __restrict__ topo,
    const float* __restrict__ lamp, const int* __restrict__ D0p,
    const int* __restrict__ slabp, ushort_t* __restrict__ Obf) {
  const int bid = blockIdx.x;
  const int hb = bid & 7;
  const int h = hb & 3, b = hb >> 2;
  const int zp = (bid >> 3) & 15;
  const int pb = bid >> 7;                 // 0..8
  const int p0 = pb * 64;
  const int tid = threadIdx.x;
  const int w = tid >> 6, lane = tid & 63;
  const int quad = lane >> 4, col = lane & 15;
  const int z = zp * 2 + (w >> 1);
  const int th = w & 1;

  const float LOG2E = 1.44269504f;
  const float lam2 = lamp[0] * LOG2E;
  const int D0 = D0p[0], slab = slabp[0];
  const float step = (float)(D0 - 1) / (float)(DZ_N - 1);

  int kkw, kka, kkb;
  {
    int z0 = (int)floorf(fmaf((float)z, step, 0.5f));
    int kv = z0 / slab;
    kkw = kv < 0 ? 0 : (kv > K_N - 1 ? K_N - 1 : kv);
    int z0a = (int)floorf(fmaf((float)(zp * 2), step, 0.5f));
    int z0b = (int)floorf(fmaf((float)(zp * 2 + 1), step, 0.5f));
    int ka = z0a / slab; ka = ka < 0 ? 0 : (ka > K_N - 1 ? K_N - 1 : ka);
    int kb = z0b / slab; kb = kb < 0 ? 0 : (kb > K_N - 1 ? K_N - 1 : kb);
    kka = ka < kb ? ka : kb;
    kkb = ka < kb ? kb : ka;
  }
  const int c_lo = (kka - 1) < 0 ? 0 : (kka - 1);
  const int c_hi = (kkb + 1) > (K_N - 1) ? (K_N - 1) : (kkb + 1);

  __shared__ ushort_t sKV[2][8192];    // dbuf: [buf][ K 8KB | V 8KB ] = 32 KB

  auto issue_fill = [&](int buf, int c, int pc) {
    const size_t cb = ((size_t)(((b * K_N + c) * 4 + h) * 9) + pc) * 4096;
#pragma unroll
    for (int j = 0; j < 4; j++) {
      const int seg = (w << 2) + j;    // 0..15
      const ushort_t* gsrc = (w < 2)
          ? (Kpk + cb + seg * 512 + lane * 8)
          : (Vtp + cb + (seg - 8) * 512 + lane * 8);
      ushort_t* ldst = &sKV[buf][seg * 512];
      __builtin_amdgcn_global_load_lds(
          (const __attribute__((address_space(1))) void*)gsrc,
          (__attribute__((address_space(3))) void*)ldst, 16, 0, 0);
    }
  };

  // ones A-frag for lsum-via-MFMA (layout-invariant: all elements 1.0bf16)
  union { ushort_t u[8]; bf16x8 v; } uo;
#pragma unroll
  for (int i = 0; i < 8; i++) uo.u[i] = 0x3F80;
  const bf16x8 vone = uo.v;

  // Q B-frags (2 tiles)
  bf16x8 bq[2][2];
  const int qrow0 = (b * DZ_N + z) * HW_N + p0 + th * 32;
#pragma unroll
  for (int t = 0; t < 2; t++) {
    const ushort_t* qp = &Qbf[(qrow0 + t * 16 + col) * E_N + h * 64 + quad * 8];
    bq[t][0] = *(const bf16x8*)qp;
    bq[t][1] = *(const bf16x8*)(qp + 32);
  }

  f32x4 oacc[2][4];
#pragma unroll
  for (int t = 0; t < 2; t++)
#pragma unroll
    for (int dt = 0; dt < 4; dt++) oacc[t][dt] = (f32x4){0.f, 0.f, 0.f, 0.f};
  f32x4 lacc[2];
  lacc[0] = (f32x4){0.f, 0.f, 0.f, 0.f};
  lacc[1] = (f32x4){0.f, 0.f, 0.f, 0.f};

  const int s7 = col & 7;
  const int o1 = (quad ^ s7) * 8;
  const int o2 = ((quad + 4) ^ s7) * 8;

  int buf = 0;
  issue_fill(0, c_lo, 0);   // prologue

  for (int c = c_lo; c <= c_hi; c++) {
    const bool act = (c >= kkw - 1) && (c <= kkw + 1);
    const float biasE2 = ((c == kkw) ? -20.0f : -20.5f) * LOG2E;
    const f32x4 bias4 = (f32x4){biasE2, biasE2, biasE2, biasE2};
    const float* topoc = &topo[(b * K_N + c) * HW_N + p0];
#pragma unroll 1
    for (int pc = 0; pc < 9; pc++) {
      __syncthreads();   // drains in-flight fill; all waves arrive
      {
        int pc2 = pc + 1, c2 = c;
        if (pc2 == 9) { pc2 = 0; c2 = c + 1; }
        if (c2 <= c_hi) issue_fill(buf ^ 1, c2, pc2);
      }
      const ushort_t* sKb = &sKV[buf][0];
      const ushort_t* sVb = &sKV[buf][4096];
      buf ^= 1;
      if (!act) continue;

      bf16x8 ka[4][2];
#pragma unroll
      for (int kt = 0; kt < 4; kt++) {
        const ushort_t* kr = sKb + (kt * 16 + col) * 64;
        ka[kt][0] = *(const bf16x8*)(kr + o1);
        ka[kt][1] = *(const bf16x8*)(kr + o2);
      }

      bf16x8 pfrag[2][2];
#pragma unroll
      for (int t = 0; t < 2; t++) {
        f32x4 sv[4];
#pragma unroll
        for (int kt = 0; kt < 4; kt++) {
          // C-operand carries scale*logit + bias: Q was pre-scaled, C=bias4.
          f32x4 acc = __builtin_amdgcn_mfma_f32_16x16x32_bf16(
              ka[kt][0], bq[t][0], bias4, 0, 0, 0);
          acc = __builtin_amdgcn_mfma_f32_16x16x32_bf16(
              ka[kt][1], bq[t][1], acc, 0, 0, 0);
          sv[kt] = acc;
        }
        float xv[4][4];
#pragma unroll
        for (int kt = 0; kt < 4; kt++)
#pragma unroll
          for (int r = 0; r < 4; r++)
            xv[kt][r] = sv[kt][r];
        if (pc == pb) {
          const int ctt = th * 2 + t;
          const float tv2 = lam2 * topoc[th * 32 + t * 16 + col];
          const bool qok = ((col >> 2) == quad);
#pragma unroll
          for (int kt = 0; kt < 4; kt++)
#pragma unroll
            for (int r = 0; r < 4; r++)
              xv[kt][r] += (qok && kt == ctt && (col & 3) == r) ? tv2 : 0.f;
        }
        float ev[4][4];
#pragma unroll
        for (int kt = 0; kt < 4; kt++)
#pragma unroll
          for (int r = 0; r < 4; r++)
            ev[kt][r] = __builtin_amdgcn_exp2f(xv[kt][r]);
#pragma unroll
        for (int f = 0; f < 2; f++) {
          union { uint4 u; bf16x8 v; } pk;
          pk.u.x = __builtin_amdgcn_perm(__float_as_uint(ev[f*2][1]),
                                         __float_as_uint(ev[f*2][0]), 0x07060302u);
          pk.u.y = __builtin_amdgcn_perm(__float_as_uint(ev[f*2][3]),
                                         __float_as_uint(ev[f*2][2]), 0x07060302u);
          pk.u.z = __builtin_amdgcn_perm(__float_as_uint(ev[f*2+1][1]),
                                         __float_as_uint(ev[f*2+1][0]), 0x07060302u);
          pk.u.w = __builtin_amdgcn_perm(__float_as_uint(ev[f*2+1][3]),
                                         __float_as_uint(ev[f*2+1][2]), 0x07060302u);
          pfrag[t][f] = pk.v;
        }
        // lsum on the MFMA pipe: ones-A column-sums of P (all D rows equal).
        lacc[t] = __builtin_amdgcn_mfma_f32_16x16x32_bf16(
            vone, pfrag[t][0], lacc[t], 0, 0, 0);
        lacc[t] = __builtin_amdgcn_mfma_f32_16x16x32_bf16(
            vone, pfrag[t][1], lacc[t], 0, 0, 0);
      }

#pragma unroll
      for (int dt = 0; dt < 4; dt++) {
        const ushort_t* vr = sVb + (dt * 16 + col) * 64;
        bf16x8 va0 = *(const bf16x8*)(vr + o1);
        bf16x8 va1 = *(const bf16x8*)(vr + o2);
#pragma unroll
        for (int t = 0; t < 2; t++) {
          oacc[t][dt] = __builtin_amdgcn_mfma_f32_16x16x32_bf16(va0, pfrag[t][0], oacc[t][dt], 0, 0, 0);
          oacc[t][dt] = __builtin_amdgcn_mfma_f32_16x16x32_bf16(va1, pfrag[t][1], oacc[t][dt], 0, 0, 0);
        }
      }
    }
  }

  // epilogue: lacc already holds full row-sum (no cross-quad reduce needed)
#pragma unroll
  for (int t = 0; t < 2; t++) {
    const float invl = 1.f / lacc[t][0];
    const int row = qrow0 + t * 16 + col;
    ushort_t* orow = &Obf[(size_t)row * E_N + h * 64];
#pragma unroll
    for (int dt = 0; dt < 4; dt++) {
      ushort4 o;
      o.x = f2bf(oacc[t][dt][0] * invl);
      o.y = f2bf(oacc[t][dt][1] * invl);
      o.z = f2bf(oacc[t][dt][2] * invl);
      o.w = f2bf(oacc[t][dt][3] * invl);
      *(ushort4*)&orow[dt * 16 + quad * 4] = o;
    }
  }
}

// ---------------------------------------------------------------------------
// Output projection (MFMA) + residual. Residual unroll x8.
// ---------------------------------------------------------------------------
__global__ __launch_bounds__(256) void out_proj_mfma(
    const ushort_t* __restrict__ Obf, const ushort_t* __restrict__ Wpp,
    const float* __restrict__ F3, float* __restrict__ outp) {
  __shared__ float sOut[64][129];
  const int tid = threadIdx.x;
  const int rowG = blockIdx.x * 64;
  const int wv = tid >> 6, lane = tid & 63;
  const int quad = lane >> 4, col = lane & 15;

  const ushort_t* xrow = &Obf[(size_t)(rowG + wv * 16 + col) * E_N + quad * 8];
  bf16x8 af[8];
#pragma unroll
  for (int ks = 0; ks < 8; ks++) af[ks] = *(const bf16x8*)&xrow[ks * 32];

#pragma unroll
  for (int nt = 0; nt < 8; nt++) {
    const ushort_t* wrow = &Wpp[(nt * 16 + col) * 256 + quad * 8];
    f32x4 a = (f32x4){0.f, 0.f, 0.f, 0.f};
#pragma unroll
    for (int ks = 0; ks < 8; ks++) {
      bf16x8 wf = *(const bf16x8*)&wrow[ks * 32];
      a = __builtin_amdgcn_mfma_f32_16x16x32_bf16(af[ks], wf, a, 0, 0, 0);
    }
#pragma unroll
    for (int r = 0; r < 4; r++)
      sOut[wv * 16 + quad * 4 + r][nt * 16 + col] = a[r];
  }
  __syncthreads();
  const int b = rowG / (DZ_N * HW_N);
  const int rem = rowG - b * DZ_N * HW_N;
  const int z = rem / HW_N;
  const int pp0 = rem - z * HW_N;
  const int pl = tid & 63, cg = tid >> 6;
#pragma unroll 8
  for (int c = cg * 32; c < cg * 32 + 32; c++) {
    const int gidx = ((b * C3_N + c) * DZ_N + z) * HW_N + pp0 + pl;
    outp[gidx] = F3[gidx] + sOut[pl][c];
  }
}

// ---------------------------------------------------------------------------
extern "C" void kernel_launch(void* const* d_in, const int* in_sizes, int n_in,
                              void* d_out, int out_size, void* d_ws, size_t ws_size,
                              hipStream_t stream) {
  (void)in_sizes; (void)n_in; (void)out_size; (void)ws_size;
  const float* F3      = (const float*)d_in[0];
  const float* F2      = (const float*)d_in[1];
  const float* Wq      = (const float*)d_in[2];
  const float* Wk      = (const float*)d_in[3];
  const float* Wv      = (const float*)d_in[4];
  const float* Wp      = (const float*)d_in[5];
  const float* ln_q_g  = (const float*)d_in[6];
  const float* ln_q_b  = (const float*)d_in[7];
  const float* ln_kv_g = (const float*)d_in[8];
  const float* ln_kv_b = (const float*)d_in[9];
  const float* conv1_w = (const float*)d_in[10];
  const float* bn_g    = (const float*)d_in[11];
  const float* bn_b    = (const float*)d_in[12];
  const float* conv2_w = (const float*)d_in[13];
  const float* conv2_b = (const float*)d_in[14];
  const float* lam     = (const float*)d_in[15];
  const int*   D0      = (const int*)d_in[16];
  const int*   slab    = (const int*)d_in[17];
  float* out = (float*)d_out;

  char* ws = (char*)d_ws;
  size_t off = 0;
  auto alloc = [&](size_t bytes) {
    void* p = ws + off;
    off += (bytes + 255) & ~(size_t)255;
    return p;
  };
  const int QROWS = B_N * DZ_N * HW_N;   // 36864
  const int KVROWS = B_N * K_N * HW_N;   // 9216
  ushort_t* Qbf = (ushort_t*)alloc((size_t)QROWS * E_N * 2);
  ushort_t* Kpk = (ushort_t*)alloc((size_t)KVROWS * E_N * 2);
  ushort_t* Vtp = (ushort_t*)alloc((size_t)KVROWS * E_N * 2);
  ushort_t* Obf = (ushort_t*)alloc((size_t)QROWS * E_N * 2);  // aliases Hp
  float* topo = (float*)alloc((size_t)B_N * K_N * HW_N * 4);
  ushort_t* Wqp = (ushort_t*)alloc(256 * 128 * 2);
  ushort_t* Wkp = (ushort_t*)alloc(256 * 96 * 2);
  ushort_t* Wvp = (ushort_t*)alloc(256 * 96 * 2);
  ushort_t* Wpp = (ushort_t*)alloc(128 * 256 * 2);
  float* Hp = (float*)Obf;   // 8*16*64*576*4 = 18.87 MB == Obf; dead b4 attn

  // 1) fused conv (512 blocks, 2/CU) + weight packing
  pre_conv_pack<<<1408, 384, 0, stream>>>(
      F2, conv1_w, Hp, Wq, Wk, Wv, Wp, Wqp, Wkp, Wvp, Wpp);
  // 2) fused Q + KV projections + topo tail (8 partials)
  proj_all<<<736, 256, 0, stream>>>(
      F3, F2, Wqp, Wkp, Wvp, Qbf, Kpk, Vtp,
      ln_q_g, ln_q_b, ln_kv_g, ln_kv_b,
      Hp, bn_g, bn_b, conv2_w, conv2_b, topo);
  // 3) attention -> bf16 O  (4-wave blocks, 2 z per block)
  attn_kernel<<<1152, 256, 0, stream>>>(
      Qbf, Kpk, Vtp, topo, lam, D0, slab, Obf);
  // 4) output projection (MFMA) + residual
  out_proj_mfma<<<QROWS / 64, 256, 0, stream>>>(Obf, Wpp, F3, out);
}